// Round 9
// baseline (846.273 us; speedup 1.0000x reference)
//
#include <hip/hip_runtime.h>
#include <hip/hip_cooperative_groups.h>
#include <math.h>

namespace cg = cooperative_groups;

#define N_ 50000
#define K_ 64
#define M_ 64
#define MAXIT 40
#define NC 782
#define BSZ 256

#define CG_TOLf  1e-6f
#define CG_REGf  1e-8f
#define TOL_ABSf 1e-14f

// ---- ws layout (floats). A reduction "line" = 32 consecutive floats (128B),
// banks are the 32 words of the line (bank = blockIdx & 31). ----
#define OFF_Y0   0                       // 64 lines x 32
#define OFF_PGN2 2048                    // 1 line x 32
#define OFF_S0   2080                    // 64
#define OFF_BAR  2144                    // 18 counters, stride 32
#define OFF_AATB 2720                    // 4 banks x 64x64
#define OFF_INV  19104                   // 64x64
#define OFF_BUFA 23200                   // 2 parity x 169 lines x 32 {y64,ahp64,h41}
#define OFF_BUFB 34016                   // 2 parity x 69 lines x 32 {w64,scal5}
#define WS_HEAD  38432
#define OFF_PB   38464                   // 40 x N_ (block-private)
#define OFF_HPB  (OFF_PB + MAXIT * N_)   // 40 x N_ (block-private)

#define BUFA_SZ  5408                    // 169*32
#define BUFB_SZ  2208                    // 69*32

__device__ __forceinline__ float wred(float v) {
#pragma unroll
  for (int m = 1; m < 64; m <<= 1) v += __shfl_xor(v, m, 64);
  return v;
}

// System-scope (cache-bypassing) accessors: always hit the coherence point.
__device__ __forceinline__ float cload(const float* p) {
  return __hip_atomic_load(p, __ATOMIC_RELAXED, __HIP_MEMORY_SCOPE_SYSTEM);
}
__device__ __forceinline__ void cstore(float* p, float v) {
  __hip_atomic_store(p, v, __ATOMIC_RELAXED, __HIP_MEMORY_SCOPE_SYSTEM);
}

// Fence-free 2-level tree barrier. All cross-block data moves via LLC
// (device atomics / system-scope ld+st); __syncthreads drains vmcnt so the
// arrival atomic orders after all prior LLC ops. No L2 flush/invalidate.
__device__ __forceinline__ void gbar(unsigned* bar, int b, int NB, unsigned ep) {
  __syncthreads();
  if (threadIdx.x == 0) {
    const int grp = b & 15;
    const unsigned gsz = (unsigned)((NB - grp + 15) >> 4);
    unsigned o = __hip_atomic_fetch_add(&bar[grp * 32], 1u, __ATOMIC_RELAXED, __HIP_MEMORY_SCOPE_AGENT);
    if (o % gsz == gsz - 1u) {
      unsigned r = __hip_atomic_fetch_add(&bar[16 * 32], 1u, __ATOMIC_RELAXED, __HIP_MEMORY_SCOPE_AGENT);
      if ((r & 15u) == 15u)
        __hip_atomic_fetch_add(&bar[17 * 32], 1u, __ATOMIC_RELAXED, __HIP_MEMORY_SCOPE_AGENT);
    }
    while (__hip_atomic_load(&bar[17 * 32], __ATOMIC_RELAXED, __HIP_MEMORY_SCOPE_SYSTEM) < ep)
      __builtin_amdgcn_s_sleep(2);
  }
  __syncthreads();
}

// Sum the 32 banks of lines [0,nl) into dst[line], PIPELINED:
// all loads issued first into statically-indexed regs (relaxed atomic loads
// have no inter-op waitcnt), then reduced. Group q = (line<<3)+part covers
// banks part*4..+3; thread t takes q = t, t+256, ... (<=6 groups, nl<=192).
// 8 consecutive lanes share a line -> shfl_xor 1/2/4 completes the line sum.
__device__ __forceinline__ void consume(const float* buf, int nl, float* dst, int t) {
  const int nq = nl * 8;
  float x[6][4];
#pragma unroll
  for (int k = 0; k < 6; ++k) {
    const int q = t + (k << 8);
    x[k][0] = 0.f; x[k][1] = 0.f; x[k][2] = 0.f; x[k][3] = 0.f;
    if (q < nq) {
      const float* p = buf + q * 4;
      x[k][0] = cload(p);
      x[k][1] = cload(p + 1);
      x[k][2] = cload(p + 2);
      x[k][3] = cload(p + 3);
    }
  }
#pragma unroll
  for (int k = 0; k < 6; ++k) {
    const int q = t + (k << 8);
    float v = (x[k][0] + x[k][1]) + (x[k][2] + x[k][3]);
    v += __shfl_xor(v, 1, 64);
    v += __shfl_xor(v, 2, 64);
    v += __shfl_xor(v, 4, 64);
    if (q < nq && (t & 7) == 0) dst[q >> 3] = v;
  }
}

__global__ __launch_bounds__(BSZ, 4)
void stcg_kernel(const float* __restrict__ g, const float* __restrict__ dg,
                 const float* __restrict__ U, const float* __restrict__ A,
                 float* __restrict__ out, float* __restrict__ ws)
{
  cg::grid_group grid = cg::this_grid();
  const int b = blockIdx.x, NB = gridDim.x, t = threadIdx.x;
  const int wv = t >> 6, lane = t & 63;
  const int base1 = b * 64;
  const int col1 = base1 + lane;
  const bool valid1 = col1 < N_;
  const bool own2 = (b + NB) < NC;            // rare fallback chunk
  const int base2 = (b + NB) * 64;
  const int col2 = base2 + lane;
  const bool valid2 = own2 && (col2 < N_);
  const int nv2 = own2 ? min(64, N_ - base2) : 0;
  const int bank = b & 31;

  __shared__ float Als[64 * 65];     // A rows for chunk1 [m][col]
  __shared__ float AHPl[41 * 65];    // per-block A*HP_j history
  __shared__ float partA[BSZ];
  __shared__ float rL[64], hpL[64], pL[64];     // hpL doubles as zL in phase 2
  __shared__ float rL2[64], hpL2[64], pL2[64];
  __shared__ float ssh[64], cshL[64];           // cshL doubles as gL in setup
  __shared__ float rowk[64], fsh[64];
  __shared__ float redL[184];
  __shared__ float pHpdL[MAXIT];

  float* Pb  = ws + OFF_PB;
  float* HPb = ws + OFF_HPB;
  unsigned* bar = (unsigned*)(ws + OFF_BAR);
  unsigned ep = 0;

  float t_ = 0.f, r_ = 0.f, p_ = 0.f, d_ = 0.f;
  float t2_ = 0.f, r2_ = 0.f, p2_ = 0.f, d2_ = 0.f;
  float invr[16];   // INV[lane][wv*16+kk]
  float ur[16];     // U^T[wv*16+kk][col1] = U[col1][wv*16+kk]
  if (wv == 0 && valid1) d_ = dg[col1];
  if (wv == 1 && valid2) d2_ = dg[col2];

  // ===== S0: zero ws head (incl. barrier counters) =====
  for (int idx = b * BSZ + t; idx < WS_HEAD; idx += NB * BSZ) ws[idx] = 0.f;
  grid.sync();   // cooperative (fenced) sync flushes the plain zero-stores

  // ===== S1: A tiles; AAt partials (4-banked); y0 = A g (32-banked lines) =====
  float aat[4][4];
#pragma unroll
  for (int a = 0; a < 4; ++a)
#pragma unroll
    for (int c = 0; c < 4; ++c) aat[a][c] = 0.f;
  const int tr4 = (t >> 4) << 2, tc4 = (t & 15) << 2;

  if (wv == 0) cshL[lane] = valid1 ? g[col1] : 0.f;   // gL
#pragma unroll
  for (int kk = 0; kk < 16; ++kk) {
    const int m = wv * 16 + kk;
    Als[m * 65 + lane] = valid1 ? A[(size_t)m * N_ + col1] : 0.f;
  }
  __syncthreads();
  {
#pragma unroll 4
    for (int j = 0; j < 64; ++j) {
      float a0 = Als[(tr4 + 0) * 65 + j], a1 = Als[(tr4 + 1) * 65 + j];
      float a2 = Als[(tr4 + 2) * 65 + j], a3 = Als[(tr4 + 3) * 65 + j];
      float b0 = Als[(tc4 + 0) * 65 + j], b1 = Als[(tc4 + 1) * 65 + j];
      float b2 = Als[(tc4 + 2) * 65 + j], b3 = Als[(tc4 + 3) * 65 + j];
      aat[0][0] += a0 * b0; aat[0][1] += a0 * b1; aat[0][2] += a0 * b2; aat[0][3] += a0 * b3;
      aat[1][0] += a1 * b0; aat[1][1] += a1 * b1; aat[1][2] += a1 * b2; aat[1][3] += a1 * b3;
      aat[2][0] += a2 * b0; aat[2][1] += a2 * b1; aat[2][2] += a2 * b2; aat[2][3] += a2 * b3;
      aat[3][0] += a3 * b0; aat[3][1] += a3 * b1; aat[3][2] += a3 * b2; aat[3][3] += a3 * b3;
    }
    if (wv == 0) {
      float s = 0.f;
#pragma unroll 8
      for (int c = 0; c < 64; ++c) s += Als[lane * 65 + c] * cshL[c];
      atomicAdd(&ws[OFF_Y0 + lane * 32 + bank], s);
    }
  }
  if (own2) {
    __syncthreads();
    if (wv == 1) cshL[lane] = valid2 ? g[col2] : 0.f;
#pragma unroll
    for (int kk = 0; kk < 16; ++kk) {
      const int m = wv * 16 + kk;
      Als[m * 65 + lane] = valid2 ? A[(size_t)m * N_ + col2] : 0.f;
    }
    __syncthreads();
#pragma unroll 4
    for (int j = 0; j < 64; ++j) {
      float a0 = Als[(tr4 + 0) * 65 + j], a1 = Als[(tr4 + 1) * 65 + j];
      float a2 = Als[(tr4 + 2) * 65 + j], a3 = Als[(tr4 + 3) * 65 + j];
      float b0 = Als[(tc4 + 0) * 65 + j], b1 = Als[(tc4 + 1) * 65 + j];
      float b2 = Als[(tc4 + 2) * 65 + j], b3 = Als[(tc4 + 3) * 65 + j];
      aat[0][0] += a0 * b0; aat[0][1] += a0 * b1; aat[0][2] += a0 * b2; aat[0][3] += a0 * b3;
      aat[1][0] += a1 * b0; aat[1][1] += a1 * b1; aat[1][2] += a1 * b2; aat[1][3] += a1 * b3;
      aat[2][0] += a2 * b0; aat[2][1] += a2 * b1; aat[2][2] += a2 * b2; aat[2][3] += a2 * b3;
      aat[3][0] += a3 * b0; aat[3][1] += a3 * b1; aat[3][2] += a3 * b2; aat[3][3] += a3 * b3;
    }
    if (wv == 1) {
      float s = 0.f;
#pragma unroll 8
      for (int c = 0; c < 64; ++c) s += Als[lane * 65 + c] * cshL[c];
      atomicAdd(&ws[OFF_Y0 + lane * 32 + bank], s);
    }
    __syncthreads();
#pragma unroll
    for (int kk = 0; kk < 16; ++kk) {   // reload chunk1 tile
      const int m = wv * 16 + kk;
      Als[m * 65 + lane] = valid1 ? A[(size_t)m * N_ + col1] : 0.f;
    }
  }
  {
    float* bk4 = ws + OFF_AATB + (b & 3) * 4096;
#pragma unroll
    for (int a = 0; a < 4; ++a)
#pragma unroll
      for (int c = 0; c < 4; ++c)
        atomicAdd(&bk4[(tr4 + a) * 64 + (tc4 + c)], aat[a][c]);
  }
  gbar(bar, b, NB, ++ep);

  // ===== S2: b0: register Gauss-Jordan inverse -> INV, s0; all: load ur =====
  if (b == 0) {
#pragma unroll
    for (int kk = 0; kk < 16; ++kk) {
      const int idx = lane * 64 + wv * 16 + kk;
      float v = cload(&ws[OFF_AATB + idx]) + cload(&ws[OFF_AATB + 4096 + idx]) +
                cload(&ws[OFF_AATB + 8192 + idx]) + cload(&ws[OFF_AATB + 12288 + idx]);
      invr[kk] = v + ((lane == wv * 16 + kk) ? 1e-8f : 0.f);
    }
    __syncthreads();
    for (int k = 0; k < 64; ++k) {
      if (lane == k) {
#pragma unroll
        for (int kk = 0; kk < 16; ++kk) rowk[wv * 16 + kk] = invr[kk];
      }
      if (wv == (k >> 4)) fsh[lane] = invr[k & 15];
      __syncthreads();
      const float piv = 1.0f / rowk[k];
      const float fr = fsh[lane];
#pragma unroll
      for (int kk = 0; kk < 16; ++kk) {
        const int c = wv * 16 + kk;
        const float rkc = rowk[c] * piv;
        float v;
        if (lane == k) v = (c == k) ? piv : rkc;
        else           v = (c == k) ? (-fr * piv) : (invr[kk] - fr * rkc);
        invr[kk] = v;
      }
      __syncthreads();
    }
#pragma unroll
    for (int kk = 0; kk < 16; ++kk)
      cstore(&ws[OFF_INV + lane * 64 + wv * 16 + kk], invr[kk]);
    if (t < 64) {
      float a = 0.f;
#pragma unroll
      for (int k2 = 0; k2 < 32; ++k2) a += cload(&ws[OFF_Y0 + t * 32 + k2]);
      redL[t] = a;
    }
    __syncthreads();
    {
      float ps = 0.f;
#pragma unroll
      for (int kk = 0; kk < 16; ++kk) ps += invr[kk] * redL[wv * 16 + kk];
      partA[t] = ps;
    }
    __syncthreads();
    if (t < 64) cstore(&ws[OFF_S0 + t], partA[t] + partA[64 + t] + partA[128 + t] + partA[192 + t]);
  }
  {  // all blocks: U row of col1 into registers (U^T fragments)
    if (valid1) {
      const float4* Up = reinterpret_cast<const float4*>(U + (size_t)col1 * K_ + wv * 16);
      float4 u0 = Up[0], u1 = Up[1], u2 = Up[2], u3 = Up[3];
      ur[0]=u0.x; ur[1]=u0.y; ur[2]=u0.z; ur[3]=u0.w;
      ur[4]=u1.x; ur[5]=u1.y; ur[6]=u1.z; ur[7]=u1.w;
      ur[8]=u2.x; ur[9]=u2.y; ur[10]=u2.z; ur[11]=u2.w;
      ur[12]=u3.x; ur[13]=u3.y; ur[14]=u3.z; ur[15]=u3.w;
    } else {
#pragma unroll
      for (int kk = 0; kk < 16; ++kk) ur[kk] = 0.f;
    }
  }
  gbar(bar, b, NB, ++ep);

  if (b != 0) {
#pragma unroll
    for (int kk = 0; kk < 16; ++kk)
      invr[kk] = cload(&ws[OFF_INV + lane * 64 + wv * 16 + kk]);
  }

  // ===== S3: r0 = A^T s0 - g; stats; w0 = U^T p0 =====
  if (t < 64) ssh[t] = cload(&ws[OFF_S0 + t]);
  __syncthreads();
  {
    float* B0 = ws + OFF_BUFB;  // parity 0
    if (wv == 0) {
      float acc = 0.f;
#pragma unroll 8
      for (int m = 0; m < 64; ++m) acc += Als[m * 65 + lane] * ssh[m];
      float r0 = valid1 ? (acc - g[col1]) : 0.f;
      r_ = r0; p_ = r0; pL[lane] = r0;
      const float v  = wred(r0 * r0);
      const float v0 = wred(d_ * r0 * r0);
      if (lane == 0) {
        atomicAdd(&B0[(64 + 0) * 32 + bank], v0);  // pDp
        atomicAdd(&B0[(64 + 1) * 32 + bank], v);   // pp
        atomicAdd(&B0[(64 + 2) * 32 + bank], v);   // rp
        atomicAdd(&B0[(64 + 3) * 32 + bank], v);   // rz
        atomicAdd(&B0[(64 + 4) * 32 + bank], v);   // zz
        atomicAdd(&ws[OFF_PGN2 + bank], v);
      }
    }
    if (wv == 1 && own2) {
      float acc = 0.f;
      if (valid2) {
#pragma unroll 8
        for (int m = 0; m < 64; ++m) acc += A[(size_t)m * N_ + col2] * ssh[m];
      }
      float r0 = valid2 ? (acc - g[col2]) : 0.f;
      r2_ = r0; p2_ = r0; pL2[lane] = r0;
      const float v  = wred(r0 * r0);
      const float v0 = wred(d2_ * r0 * r0);
      if (lane == 0) {
        atomicAdd(&B0[(64 + 0) * 32 + bank], v0);
        atomicAdd(&B0[(64 + 1) * 32 + bank], v);
        atomicAdd(&B0[(64 + 2) * 32 + bank], v);
        atomicAdd(&B0[(64 + 3) * 32 + bank], v);
        atomicAdd(&B0[(64 + 4) * 32 + bank], v);
        atomicAdd(&ws[OFF_PGN2 + bank], v);
      }
    }
    __syncthreads();
    // w0: each wave covers its 16 k's via register U^T fragments
#pragma unroll
    for (int kk = 0; kk < 16; ++kk) {
      const float s = wred(ur[kk] * pL[lane]);
      if (lane == 0) atomicAdd(&B0[(wv * 16 + kk) * 32 + bank], s);
    }
    if (wv == 1 && own2) {
      float s = 0.f;
      for (int c = 0; c < nv2; ++c) s += U[(size_t)(base2 + c) * K_ + lane] * pL2[c];
      atomicAdd(&B0[lane * 32 + bank], s);
    }
  }
  gbar(bar, b, NB, ++ep);

  // ===== main loop =====
  float pgn2v = 0.f;
#pragma unroll
  for (int k = 0; k < 32; ++k) pgn2v += cload(&ws[OFF_PGN2 + k]);
  const float pgn = sqrtf(fmaxf(pgn2v, 0.f));
  const float tolv = fmaxf(TOL_ABSf, CG_TOLf * pgn);
  bool sc_r = false, convf = false;

  for (int it = 0;; ++it) {
    const int p = it & 1;
    float* BB  = ws + OFF_BUFB + p * BUFB_SZ;
    float* BBn = ws + OFF_BUFB + (p ^ 1) * BUFB_SZ;
    float* BA  = ws + OFF_BUFA + p * BUFA_SZ;
    float* BAn = ws + OFF_BUFA + (p ^ 1) * BUFA_SZ;

    consume(BB, 69, redL, t);   // w[0..64) + scalars[64..69) -> redL
    for (int u = b * BSZ + t; u < BUFB_SZ; u += NB * BSZ) cstore(&BBn[u], 0.f);
    __syncthreads();
    const float pDp = redL[64], pp = redL[65], rp = redL[66], rz = redL[67], zz = redL[68];
    convf = sc_r || (sqrtf(fmaxf(zz, 0.f)) <= tolv);
    if (convf || it == MAXIT) break;

    const float ww = wred(redL[lane] * redL[lane]);
    const float pHp = pDp + ww;
    const bool bad = pHp <= fmaxf(CG_REGf * pp, CG_REGf * pgn2v);
    sc_r = bad || (fabsf(rp) < 1e-30f);
    const float alpha = sc_r ? 0.f : rz / fmaxf(pHp, 1e-30f);
    if (t == 0) pHpdL[it] = pHp;

    // ---- phase 1: Hp; t/r update; store P/HP (private); reduce y/ahp/h ----
    {
      float acc = 0.f;
#pragma unroll
      for (int kk = 0; kk < 16; ++kk) acc += ur[kk] * redL[wv * 16 + kk];
      partA[t] = acc;
    }
    __syncthreads();
    if (wv == 0) {
      const float hp = d_ * p_ + partA[lane] + partA[64 + lane] + partA[128 + lane] + partA[192 + lane];
      t_ += alpha * p_;
      r_ -= alpha * hp;
      if (valid1) { Pb[(size_t)it * N_ + col1] = p_; HPb[(size_t)it * N_ + col1] = hp; }
      rL[lane] = r_; hpL[lane] = hp;
    }
    if (wv == 1 && own2) {
      float hp = d2_ * p2_;
      if (valid2) {
        const float4* Urow = reinterpret_cast<const float4*>(U + (size_t)col2 * K_);
#pragma unroll
        for (int k4 = 0; k4 < 16; ++k4) {
          float4 u = Urow[k4];
          hp += u.x * redL[4 * k4 + 0] + u.y * redL[4 * k4 + 1] + u.z * redL[4 * k4 + 2] + u.w * redL[4 * k4 + 3];
        }
      }
      t2_ += alpha * p2_;
      r2_ -= alpha * hp;
      if (valid2) { Pb[(size_t)it * N_ + col2] = p2_; HPb[(size_t)it * N_ + col2] = hp; }
      rL2[lane] = r2_; hpL2[lane] = hp;
    }
    __syncthreads();
    if (wv == 0) {
      float sy = 0.f, sa = 0.f;
#pragma unroll 8
      for (int c = 0; c < 64; ++c) {
        const float av = Als[lane * 65 + c];
        sy += av * rL[c];
        sa += av * hpL[c];
      }
      atomicAdd(&BA[lane * 32 + bank], sy);
      atomicAdd(&BA[(64 + lane) * 32 + bank], sa);
    } else if (wv == 1 && own2) {
      float sy = 0.f, sa = 0.f;
      for (int c = 0; c < nv2; ++c) {
        const float av = A[(size_t)lane * N_ + base2 + c];
        sy += av * rL2[c];
        sa += av * hpL2[c];
      }
      atomicAdd(&BA[lane * 32 + bank], sy);
      atomicAdd(&BA[(64 + lane) * 32 + bank], sa);
    }
    {
      const int hw0 = own2 ? 2 : 1;
      if (wv >= hw0) {
        const int nhw = 4 - hw0;
        for (int j = wv - hw0; j <= it; j += nhw) {
          float s = ((j == it) ? hpL[lane] : (valid1 ? HPb[(size_t)j * N_ + col1] : 0.f)) * rL[lane];
          if (own2) {
            const float hv2 = (j == it) ? hpL2[lane] : (valid2 ? HPb[(size_t)j * N_ + col2] : 0.f);
            s += hv2 * rL2[lane];
          }
          s = wred(s);
          if (lane == 0) atomicAdd(&BA[(128 + j) * 32 + bank], s);
        }
      }
    }
    gbar(bar, b, NB, ++ep);

    // ---- phase 2: s (reg matvec); coeffs; z, p_new; reduce w + scalars ----
    consume(BA, 129 + it, redL, t);
    for (int u = b * BSZ + t; u < BUFA_SZ; u += NB * BSZ) cstore(&BAn[u], 0.f);
    __syncthreads();
    if (t < 64) AHPl[it * 65 + t] = redL[64 + t];
    {
      float ps = 0.f;
#pragma unroll
      for (int kk = 0; kk < 16; ++kk) ps += invr[kk] * redL[wv * 16 + kk];
      partA[t] = ps;
    }
    __syncthreads();
    if (t < 64) ssh[t] = partA[t] + partA[64 + t] + partA[128 + t] + partA[192 + t];
    __syncthreads();
    if (t < 64) {
      float c = 0.f;
      if (t <= it) {
        float hz = redL[128 + t];
        const float* ar = AHPl + t * 65;
#pragma unroll 8
        for (int m = 0; m < 64; ++m) hz -= ar[m] * ssh[m];
        const float den = pHpdL[t];
        c = hz / ((fabsf(den) > 1e-30f) ? den : 1e-30f);
      }
      cshL[t] = c;
    }
    __syncthreads();
    {
      float accA = 0.f;
#pragma unroll
      for (int kk = 0; kk < 16; ++kk) {
        const int m = wv * 16 + kk;
        accA += Als[m * 65 + lane] * ssh[m];
      }
      partA[t] = accA;
    }
    __syncthreads();
    if (wv == 0) {
      float z = r_ - (partA[lane] + partA[64 + lane] + partA[128 + lane] + partA[192 + lane]);
      if (!valid1) z = 0.f;
      hpL[lane] = z;   // zL
    }
    if (wv == 1 && own2) {
      float acc = 0.f;
      if (valid2) {
#pragma unroll 8
        for (int m = 0; m < 64; ++m) acc += A[(size_t)m * N_ + col2] * ssh[m];
      }
      hpL2[lane] = valid2 ? (r2_ - acc) : 0.f;
    }
    __syncthreads();
    {
      float accP = 0.f;
      if (valid1) {
        for (int j = wv; j <= it; j += 4) accP += cshL[j] * Pb[(size_t)j * N_ + col1];
      }
      partA[t] = accP;
    }
    __syncthreads();
    if (wv == 0) {
      const float z = hpL[lane];
      float pn = z - (partA[lane] + partA[64 + lane] + partA[128 + lane] + partA[192 + lane]);
      if (!valid1) pn = 0.f;
      p_ = pn; pL[lane] = pn;
      const float v0 = wred(d_ * pn * pn);
      const float v1 = wred(pn * pn);
      const float v2 = wred(r_ * pn);
      const float v3 = wred(r_ * z);
      const float v4 = wred(z * z);
      if (lane == 0) {
        atomicAdd(&BBn[(64 + 0) * 32 + bank], v0);
        atomicAdd(&BBn[(64 + 1) * 32 + bank], v1);
        atomicAdd(&BBn[(64 + 2) * 32 + bank], v2);
        atomicAdd(&BBn[(64 + 3) * 32 + bank], v3);
        atomicAdd(&BBn[(64 + 4) * 32 + bank], v4);
      }
    }
    if (wv == 1 && own2) {
      const float z2 = hpL2[lane];
      float accP2 = 0.f;
      if (valid2) {
        for (int j = 0; j <= it; ++j) accP2 += cshL[j] * Pb[(size_t)j * N_ + col2];
      }
      float pn = valid2 ? (z2 - accP2) : 0.f;
      p2_ = pn; pL2[lane] = pn;
      const float v0 = wred(d2_ * pn * pn);
      const float v1 = wred(pn * pn);
      const float v2 = wred(r2_ * pn);
      const float v3 = wred(r2_ * z2);
      const float v4 = wred(z2 * z2);
      if (lane == 0) {
        atomicAdd(&BBn[(64 + 0) * 32 + bank], v0);
        atomicAdd(&BBn[(64 + 1) * 32 + bank], v1);
        atomicAdd(&BBn[(64 + 2) * 32 + bank], v2);
        atomicAdd(&BBn[(64 + 3) * 32 + bank], v3);
        atomicAdd(&BBn[(64 + 4) * 32 + bank], v4);
      }
    }
    __syncthreads();
#pragma unroll
    for (int kk = 0; kk < 16; ++kk) {
      const float s = wred(ur[kk] * pL[lane]);
      if (lane == 0) atomicAdd(&BBn[(wv * 16 + kk) * 32 + bank], s);
    }
    if (wv == 1 && own2) {
      float s = 0.f;
      for (int c = 0; c < nv2; ++c) s += U[(size_t)(base2 + c) * K_ + lane] * pL2[c];
      atomicAdd(&BBn[lane * 32 + bank], s);
    }
    gbar(bar, b, NB, ++ep);
  }

  // ===== epilogue =====
  if (wv == 0 && valid1) out[col1] = t_;
  if (wv == 1 && valid2) out[col2] = t2_;
  if (b == 0 && t == 0) {
    out[N_]     = pgn;
    out[N_ + 1] = convf ? 1.f : 0.f;
  }
}

extern "C" void kernel_launch(void* const* d_in, const int* in_sizes, int n_in,
                              void* d_out, int out_size, void* d_ws, size_t ws_size,
                              hipStream_t stream) {
  (void)in_sizes; (void)n_in; (void)out_size; (void)ws_size;
  const float* g  = (const float*)d_in[0];
  const float* dg = (const float*)d_in[1];
  const float* U  = (const float*)d_in[2];
  const float* A  = (const float*)d_in[3];
  float* out = (float*)d_out;
  float* ws  = (float*)d_ws;

  // Grid strictly from the occupancy API (R2/R5/R7 lesson).
  int dev = 0;
  hipGetDevice(&dev);
  int nCU = 0;
  hipDeviceGetAttribute(&nCU, hipDeviceAttributeMultiprocessorCount, dev);
  if (nCU <= 0) nCU = 256;
  int maxB = 0;
  hipOccupancyMaxActiveBlocksPerMultiprocessor(&maxB, stcg_kernel, BSZ, 0);
  if (maxB <= 0) maxB = 1;
  int nblk = maxB * nCU;
  if (nblk > NC) nblk = NC;
  if (nblk < 391) nblk = 391;  // 2-chunk fallback floor (ceil(782/2))

  void* args[] = {(void*)&g, (void*)&dg, (void*)&U, (void*)&A, (void*)&out, (void*)&ws};
  hipLaunchCooperativeKernel(stcg_kernel, dim3(nblk), dim3(BSZ), args, 0, stream);
}

// Round 10
// 623.909 us; speedup vs baseline: 1.3564x; 1.3564x over previous
//
#include <hip/hip_runtime.h>
#include <hip/hip_cooperative_groups.h>
#include <math.h>

namespace cg = cooperative_groups;

#define N_ 50000
#define K_ 64
#define M_ 64
#define MAXIT 40
#define NC 782
#define BSZ 256

#define CG_TOLf  1e-6f
#define CG_REGf  1e-8f
#define TOL_ABSf 1e-14f

// ---- ws layout (floats). A reduction "line" = 32 consecutive floats (128B),
// banks are the 32 words of the line (bank = blockIdx & 31). ----
#define OFF_Y0   0                       // 64 lines x 32
#define OFF_PGN2 2048                    // 1 line x 32
#define OFF_S0   2080                    // 64
#define OFF_BAR  2144                    // 18 counters, stride 32
#define OFF_AATB 2720                    // 4 banks x 64x64
#define OFF_INV  19104                   // 64x64
#define OFF_BUFA 23200                   // 2 parity x 169 lines x 32 {y64,ahp64,h41}
#define OFF_BUFB 34016                   // 2 parity x 69 lines x 32 {w64,scal5}
#define WS_HEAD  38432
#define OFF_PB   38464                   // 40 x N_ (block-private)
#define OFF_HPB  (OFF_PB + MAXIT * N_)   // 40 x N_ (block-private)

#define BUFA_SZ  5408                    // 169*32
#define BUFB_SZ  2208                    // 69*32

__device__ __forceinline__ float wred(float v) {
#pragma unroll
  for (int m = 1; m < 64; m <<= 1) v += __shfl_xor(v, m, 64);
  return v;
}

// System-scope (cache-bypassing) accessors: always hit the coherence point.
__device__ __forceinline__ float cload(const float* p) {
  return __hip_atomic_load(p, __ATOMIC_RELAXED, __HIP_MEMORY_SCOPE_SYSTEM);
}
__device__ __forceinline__ void cstore(float* p, float v) {
  __hip_atomic_store(p, v, __ATOMIC_RELAXED, __HIP_MEMORY_SCOPE_SYSTEM);
}

// Fence-free 2-level tree barrier (R8-proven).
__device__ __forceinline__ void gbar(unsigned* bar, int b, int NB, unsigned ep) {
  __syncthreads();
  if (threadIdx.x == 0) {
    const int grp = b & 15;
    const unsigned gsz = (unsigned)((NB - grp + 15) >> 4);
    unsigned o = __hip_atomic_fetch_add(&bar[grp * 32], 1u, __ATOMIC_RELAXED, __HIP_MEMORY_SCOPE_AGENT);
    if (o % gsz == gsz - 1u) {
      unsigned r = __hip_atomic_fetch_add(&bar[16 * 32], 1u, __ATOMIC_RELAXED, __HIP_MEMORY_SCOPE_AGENT);
      if ((r & 15u) == 15u)
        __hip_atomic_fetch_add(&bar[17 * 32], 1u, __ATOMIC_RELAXED, __HIP_MEMORY_SCOPE_AGENT);
    }
    while (__hip_atomic_load(&bar[17 * 32], __ATOMIC_RELAXED, __HIP_MEMORY_SCOPE_SYSTEM) < ep)
      __builtin_amdgcn_s_sleep(2);
  }
  __syncthreads();
}

// Sum the 32 banks of lines [0,nl) into dst[line]. COALESCED + PIPELINED:
// lane t takes float2-group q = t + k*256 (contiguous across lanes -> one
// 512B transaction per wave-instruction; dwordx2 sc0 sc1). All NK loads are
// issued into statically-indexed regs before any use (single vmcnt fill),
// then reduced: 1 add + shfl_xor{1,2,4,8} across the 16 lanes of each line.
// nq is a multiple of 16 so each 16-lane shfl group is uniformly valid;
// clamped loads (branch-free) touch line nq-1 only, never contaminate.
template<int NK>
__device__ __forceinline__ void consume(const float* buf, int nl, float* dst, int t) {
  const int nq = nl * 16;
  const double* bd = (const double*)buf;
  double xd[NK];
#pragma unroll
  for (int k = 0; k < NK; ++k) {
    int q = t + (k << 8);
    q = (q < nq) ? q : (nq - 1);
    xd[k] = __hip_atomic_load(bd + q, __ATOMIC_RELAXED, __HIP_MEMORY_SCOPE_SYSTEM);
  }
#pragma unroll
  for (int k = 0; k < NK; ++k) {
    const int q = t + (k << 8);
    float2 f;
    __builtin_memcpy(&f, &xd[k], 8);
    float v = f.x + f.y;
    v += __shfl_xor(v, 1, 64);
    v += __shfl_xor(v, 2, 64);
    v += __shfl_xor(v, 4, 64);
    v += __shfl_xor(v, 8, 64);
    if (q < nq && (t & 15) == 0) dst[q >> 4] = v;
  }
}

__global__ __launch_bounds__(BSZ, 4)
void stcg_kernel(const float* __restrict__ g, const float* __restrict__ dg,
                 const float* __restrict__ U, const float* __restrict__ A,
                 float* __restrict__ out, float* __restrict__ ws)
{
  cg::grid_group grid = cg::this_grid();
  const int b = blockIdx.x, NB = gridDim.x, t = threadIdx.x;
  const int wv = t >> 6, lane = t & 63;
  const int base1 = b * 64;
  const int col1 = base1 + lane;
  const bool valid1 = col1 < N_;
  const bool own2 = (b + NB) < NC;            // rare fallback chunk
  const int base2 = (b + NB) * 64;
  const int col2 = base2 + lane;
  const bool valid2 = own2 && (col2 < N_);
  const int nv2 = own2 ? min(64, N_ - base2) : 0;
  const int bank = b & 31;

  __shared__ float Als[64 * 65];     // A rows for chunk1 [m][col]
  __shared__ float AHPl[41 * 65];    // per-block A*HP_j history
  __shared__ float partA[BSZ];
  __shared__ float rL[64], hpL[64], pL[64];     // hpL doubles as zL in phase 2
  __shared__ float rL2[64], hpL2[64], pL2[64];
  __shared__ float ssh[64], cshL[64];           // cshL doubles as gL in setup
  __shared__ float rowk[64], fsh[64];
  __shared__ float redL[184];
  __shared__ float pHpdL[MAXIT];

  float* Pb  = ws + OFF_PB;
  float* HPb = ws + OFF_HPB;
  unsigned* bar = (unsigned*)(ws + OFF_BAR);
  unsigned ep = 0;

  float t_ = 0.f, r_ = 0.f, p_ = 0.f, d_ = 0.f;
  float t2_ = 0.f, r2_ = 0.f, p2_ = 0.f, d2_ = 0.f;
  float invr[16];   // INV[lane][wv*16+kk]
  float ur[16];     // U^T[wv*16+kk][col1] = U[col1][wv*16+kk]
  if (wv == 0 && valid1) d_ = dg[col1];
  if (wv == 1 && valid2) d2_ = dg[col2];

  // ===== S0: zero ws head (incl. barrier counters) =====
  for (int idx = b * BSZ + t; idx < WS_HEAD; idx += NB * BSZ) ws[idx] = 0.f;
  grid.sync();   // cooperative (fenced) sync flushes the plain zero-stores

  // ===== S1: A tiles; AAt partials (4-banked); y0 = A g (32-banked lines) =====
  float aat[4][4];
#pragma unroll
  for (int a = 0; a < 4; ++a)
#pragma unroll
    for (int c = 0; c < 4; ++c) aat[a][c] = 0.f;
  const int tr4 = (t >> 4) << 2, tc4 = (t & 15) << 2;

  if (wv == 0) cshL[lane] = valid1 ? g[col1] : 0.f;   // gL
#pragma unroll
  for (int kk = 0; kk < 16; ++kk) {
    const int m = wv * 16 + kk;
    Als[m * 65 + lane] = valid1 ? A[(size_t)m * N_ + col1] : 0.f;
  }
  __syncthreads();
  {
#pragma unroll 4
    for (int j = 0; j < 64; ++j) {
      float a0 = Als[(tr4 + 0) * 65 + j], a1 = Als[(tr4 + 1) * 65 + j];
      float a2 = Als[(tr4 + 2) * 65 + j], a3 = Als[(tr4 + 3) * 65 + j];
      float b0 = Als[(tc4 + 0) * 65 + j], b1 = Als[(tc4 + 1) * 65 + j];
      float b2 = Als[(tc4 + 2) * 65 + j], b3 = Als[(tc4 + 3) * 65 + j];
      aat[0][0] += a0 * b0; aat[0][1] += a0 * b1; aat[0][2] += a0 * b2; aat[0][3] += a0 * b3;
      aat[1][0] += a1 * b0; aat[1][1] += a1 * b1; aat[1][2] += a1 * b2; aat[1][3] += a1 * b3;
      aat[2][0] += a2 * b0; aat[2][1] += a2 * b1; aat[2][2] += a2 * b2; aat[2][3] += a2 * b3;
      aat[3][0] += a3 * b0; aat[3][1] += a3 * b1; aat[3][2] += a3 * b2; aat[3][3] += a3 * b3;
    }
    if (wv == 0) {
      float s = 0.f;
#pragma unroll 8
      for (int c = 0; c < 64; ++c) s += Als[lane * 65 + c] * cshL[c];
      atomicAdd(&ws[OFF_Y0 + lane * 32 + bank], s);
    }
  }
  if (own2) {
    __syncthreads();
    if (wv == 1) cshL[lane] = valid2 ? g[col2] : 0.f;
#pragma unroll
    for (int kk = 0; kk < 16; ++kk) {
      const int m = wv * 16 + kk;
      Als[m * 65 + lane] = valid2 ? A[(size_t)m * N_ + col2] : 0.f;
    }
    __syncthreads();
#pragma unroll 4
    for (int j = 0; j < 64; ++j) {
      float a0 = Als[(tr4 + 0) * 65 + j], a1 = Als[(tr4 + 1) * 65 + j];
      float a2 = Als[(tr4 + 2) * 65 + j], a3 = Als[(tr4 + 3) * 65 + j];
      float b0 = Als[(tc4 + 0) * 65 + j], b1 = Als[(tc4 + 1) * 65 + j];
      float b2 = Als[(tc4 + 2) * 65 + j], b3 = Als[(tc4 + 3) * 65 + j];
      aat[0][0] += a0 * b0; aat[0][1] += a0 * b1; aat[0][2] += a0 * b2; aat[0][3] += a0 * b3;
      aat[1][0] += a1 * b0; aat[1][1] += a1 * b1; aat[1][2] += a1 * b2; aat[1][3] += a1 * b3;
      aat[2][0] += a2 * b0; aat[2][1] += a2 * b1; aat[2][2] += a2 * b2; aat[2][3] += a2 * b3;
      aat[3][0] += a3 * b0; aat[3][1] += a3 * b1; aat[3][2] += a3 * b2; aat[3][3] += a3 * b3;
    }
    if (wv == 1) {
      float s = 0.f;
#pragma unroll 8
      for (int c = 0; c < 64; ++c) s += Als[lane * 65 + c] * cshL[c];
      atomicAdd(&ws[OFF_Y0 + lane * 32 + bank], s);
    }
    __syncthreads();
#pragma unroll
    for (int kk = 0; kk < 16; ++kk) {   // reload chunk1 tile
      const int m = wv * 16 + kk;
      Als[m * 65 + lane] = valid1 ? A[(size_t)m * N_ + col1] : 0.f;
    }
  }
  {
    float* bk4 = ws + OFF_AATB + (b & 3) * 4096;
#pragma unroll
    for (int a = 0; a < 4; ++a)
#pragma unroll
      for (int c = 0; c < 4; ++c)
        atomicAdd(&bk4[(tr4 + a) * 64 + (tc4 + c)], aat[a][c]);
  }
  gbar(bar, b, NB, ++ep);

  // ===== S2: b0: register Gauss-Jordan inverse -> INV, s0; all: load ur =====
  if (b == 0) {
#pragma unroll
    for (int kk = 0; kk < 16; ++kk) {
      const int idx = lane * 64 + wv * 16 + kk;
      float v = cload(&ws[OFF_AATB + idx]) + cload(&ws[OFF_AATB + 4096 + idx]) +
                cload(&ws[OFF_AATB + 8192 + idx]) + cload(&ws[OFF_AATB + 12288 + idx]);
      invr[kk] = v + ((lane == wv * 16 + kk) ? 1e-8f : 0.f);
    }
    __syncthreads();
    for (int k = 0; k < 64; ++k) {
      if (lane == k) {
#pragma unroll
        for (int kk = 0; kk < 16; ++kk) rowk[wv * 16 + kk] = invr[kk];
      }
      if (wv == (k >> 4)) fsh[lane] = invr[k & 15];
      __syncthreads();
      const float piv = 1.0f / rowk[k];
      const float fr = fsh[lane];
#pragma unroll
      for (int kk = 0; kk < 16; ++kk) {
        const int c = wv * 16 + kk;
        const float rkc = rowk[c] * piv;
        float v;
        if (lane == k) v = (c == k) ? piv : rkc;
        else           v = (c == k) ? (-fr * piv) : (invr[kk] - fr * rkc);
        invr[kk] = v;
      }
      __syncthreads();
    }
#pragma unroll
    for (int kk = 0; kk < 16; ++kk)
      cstore(&ws[OFF_INV + lane * 64 + wv * 16 + kk], invr[kk]);
    if (t < 64) {
      float a = 0.f;
#pragma unroll
      for (int k2 = 0; k2 < 32; ++k2) a += cload(&ws[OFF_Y0 + t * 32 + k2]);
      redL[t] = a;
    }
    __syncthreads();
    {
      float ps = 0.f;
#pragma unroll
      for (int kk = 0; kk < 16; ++kk) ps += invr[kk] * redL[wv * 16 + kk];
      partA[t] = ps;
    }
    __syncthreads();
    if (t < 64) cstore(&ws[OFF_S0 + t], partA[t] + partA[64 + t] + partA[128 + t] + partA[192 + t]);
  }
  {  // all blocks: U row of col1 into registers (U^T fragments)
    if (valid1) {
      const float4* Up = reinterpret_cast<const float4*>(U + (size_t)col1 * K_ + wv * 16);
      float4 u0 = Up[0], u1 = Up[1], u2 = Up[2], u3 = Up[3];
      ur[0]=u0.x; ur[1]=u0.y; ur[2]=u0.z; ur[3]=u0.w;
      ur[4]=u1.x; ur[5]=u1.y; ur[6]=u1.z; ur[7]=u1.w;
      ur[8]=u2.x; ur[9]=u2.y; ur[10]=u2.z; ur[11]=u2.w;
      ur[12]=u3.x; ur[13]=u3.y; ur[14]=u3.z; ur[15]=u3.w;
    } else {
#pragma unroll
      for (int kk = 0; kk < 16; ++kk) ur[kk] = 0.f;
    }
  }
  gbar(bar, b, NB, ++ep);

  if (b != 0) {
#pragma unroll
    for (int kk = 0; kk < 16; ++kk)
      invr[kk] = cload(&ws[OFF_INV + lane * 64 + wv * 16 + kk]);
  }

  // ===== S3: r0 = A^T s0 - g; stats; w0 = U^T p0 =====
  if (t < 64) ssh[t] = cload(&ws[OFF_S0 + t]);
  __syncthreads();
  {
    float* B0 = ws + OFF_BUFB;  // parity 0
    if (wv == 0) {
      float acc = 0.f;
#pragma unroll 8
      for (int m = 0; m < 64; ++m) acc += Als[m * 65 + lane] * ssh[m];
      float r0 = valid1 ? (acc - g[col1]) : 0.f;
      r_ = r0; p_ = r0; pL[lane] = r0;
      const float v  = wred(r0 * r0);
      const float v0 = wred(d_ * r0 * r0);
      if (lane == 0) {
        atomicAdd(&B0[(64 + 0) * 32 + bank], v0);  // pDp
        atomicAdd(&B0[(64 + 1) * 32 + bank], v);   // pp
        atomicAdd(&B0[(64 + 2) * 32 + bank], v);   // rp
        atomicAdd(&B0[(64 + 3) * 32 + bank], v);   // rz
        atomicAdd(&B0[(64 + 4) * 32 + bank], v);   // zz
        atomicAdd(&ws[OFF_PGN2 + bank], v);
      }
    }
    if (wv == 1 && own2) {
      float acc = 0.f;
      if (valid2) {
#pragma unroll 8
        for (int m = 0; m < 64; ++m) acc += A[(size_t)m * N_ + col2] * ssh[m];
      }
      float r0 = valid2 ? (acc - g[col2]) : 0.f;
      r2_ = r0; p2_ = r0; pL2[lane] = r0;
      const float v  = wred(r0 * r0);
      const float v0 = wred(d2_ * r0 * r0);
      if (lane == 0) {
        atomicAdd(&B0[(64 + 0) * 32 + bank], v0);
        atomicAdd(&B0[(64 + 1) * 32 + bank], v);
        atomicAdd(&B0[(64 + 2) * 32 + bank], v);
        atomicAdd(&B0[(64 + 3) * 32 + bank], v);
        atomicAdd(&B0[(64 + 4) * 32 + bank], v);
        atomicAdd(&ws[OFF_PGN2 + bank], v);
      }
    }
    __syncthreads();
    // w0: each wave covers its 16 k's via register U^T fragments
#pragma unroll
    for (int kk = 0; kk < 16; ++kk) {
      const float s = wred(ur[kk] * pL[lane]);
      if (lane == 0) atomicAdd(&B0[(wv * 16 + kk) * 32 + bank], s);
    }
    if (wv == 1 && own2) {
      float s = 0.f;
      for (int c = 0; c < nv2; ++c) s += U[(size_t)(base2 + c) * K_ + lane] * pL2[c];
      atomicAdd(&B0[lane * 32 + bank], s);
    }
  }
  gbar(bar, b, NB, ++ep);

  // ===== main loop =====
  float pgn2v = 0.f;
#pragma unroll
  for (int k = 0; k < 32; ++k) pgn2v += cload(&ws[OFF_PGN2 + k]);
  const float pgn = sqrtf(fmaxf(pgn2v, 0.f));
  const float tolv = fmaxf(TOL_ABSf, CG_TOLf * pgn);
  bool sc_r = false, convf = false;

  for (int it = 0;; ++it) {
    const int p = it & 1;
    float* BB  = ws + OFF_BUFB + p * BUFB_SZ;
    float* BBn = ws + OFF_BUFB + (p ^ 1) * BUFB_SZ;
    float* BA  = ws + OFF_BUFA + p * BUFA_SZ;
    float* BAn = ws + OFF_BUFA + (p ^ 1) * BUFA_SZ;

    consume<5>(BB, 69, redL, t);   // w[0..64) + scalars[64..69) -> redL
    for (int u = b * BSZ + t; u < BUFB_SZ; u += NB * BSZ) cstore(&BBn[u], 0.f);
    __syncthreads();
    const float pDp = redL[64], pp = redL[65], rp = redL[66], rz = redL[67], zz = redL[68];
    convf = sc_r || (sqrtf(fmaxf(zz, 0.f)) <= tolv);
    if (convf || it == MAXIT) break;

    const float ww = wred(redL[lane] * redL[lane]);
    const float pHp = pDp + ww;
    const bool bad = pHp <= fmaxf(CG_REGf * pp, CG_REGf * pgn2v);
    sc_r = bad || (fabsf(rp) < 1e-30f);
    const float alpha = sc_r ? 0.f : rz / fmaxf(pHp, 1e-30f);
    if (t == 0) pHpdL[it] = pHp;

    // ---- phase 1: Hp; t/r update; store P/HP (private); reduce y/ahp/h ----
    {
      float acc = 0.f;
#pragma unroll
      for (int kk = 0; kk < 16; ++kk) acc += ur[kk] * redL[wv * 16 + kk];
      partA[t] = acc;
    }
    __syncthreads();
    if (wv == 0) {
      const float hp = d_ * p_ + partA[lane] + partA[64 + lane] + partA[128 + lane] + partA[192 + lane];
      t_ += alpha * p_;
      r_ -= alpha * hp;
      if (valid1) { Pb[(size_t)it * N_ + col1] = p_; HPb[(size_t)it * N_ + col1] = hp; }
      rL[lane] = r_; hpL[lane] = hp;
    }
    if (wv == 1 && own2) {
      float hp = d2_ * p2_;
      if (valid2) {
        const float4* Urow = reinterpret_cast<const float4*>(U + (size_t)col2 * K_);
#pragma unroll
        for (int k4 = 0; k4 < 16; ++k4) {
          float4 u = Urow[k4];
          hp += u.x * redL[4 * k4 + 0] + u.y * redL[4 * k4 + 1] + u.z * redL[4 * k4 + 2] + u.w * redL[4 * k4 + 3];
        }
      }
      t2_ += alpha * p2_;
      r2_ -= alpha * hp;
      if (valid2) { Pb[(size_t)it * N_ + col2] = p2_; HPb[(size_t)it * N_ + col2] = hp; }
      rL2[lane] = r2_; hpL2[lane] = hp;
    }
    __syncthreads();
    if (wv == 0) {
      float sy = 0.f, sa = 0.f;
#pragma unroll 8
      for (int c = 0; c < 64; ++c) {
        const float av = Als[lane * 65 + c];
        sy += av * rL[c];
        sa += av * hpL[c];
      }
      atomicAdd(&BA[lane * 32 + bank], sy);
      atomicAdd(&BA[(64 + lane) * 32 + bank], sa);
    } else if (wv == 1 && own2) {
      float sy = 0.f, sa = 0.f;
      for (int c = 0; c < nv2; ++c) {
        const float av = A[(size_t)lane * N_ + base2 + c];
        sy += av * rL2[c];
        sa += av * hpL2[c];
      }
      atomicAdd(&BA[lane * 32 + bank], sy);
      atomicAdd(&BA[(64 + lane) * 32 + bank], sa);
    }
    {
      const int hw0 = own2 ? 2 : 1;
      if (wv >= hw0) {
        const int nhw = 4 - hw0;
        for (int j = wv - hw0; j <= it; j += nhw) {
          float s = ((j == it) ? hpL[lane] : (valid1 ? HPb[(size_t)j * N_ + col1] : 0.f)) * rL[lane];
          if (own2) {
            const float hv2 = (j == it) ? hpL2[lane] : (valid2 ? HPb[(size_t)j * N_ + col2] : 0.f);
            s += hv2 * rL2[lane];
          }
          s = wred(s);
          if (lane == 0) atomicAdd(&BA[(128 + j) * 32 + bank], s);
        }
      }
    }
    gbar(bar, b, NB, ++ep);

    // ---- phase 2: s (reg matvec); coeffs; z, p_new; reduce w + scalars ----
    consume<11>(BA, 129 + it, redL, t);
    for (int u = b * BSZ + t; u < BUFA_SZ; u += NB * BSZ) cstore(&BAn[u], 0.f);
    __syncthreads();
    if (t < 64) AHPl[it * 65 + t] = redL[64 + t];
    {
      float ps = 0.f;
#pragma unroll
      for (int kk = 0; kk < 16; ++kk) ps += invr[kk] * redL[wv * 16 + kk];
      partA[t] = ps;
    }
    __syncthreads();
    if (t < 64) ssh[t] = partA[t] + partA[64 + t] + partA[128 + t] + partA[192 + t];
    __syncthreads();
    if (t < 64) {
      float c = 0.f;
      if (t <= it) {
        float hz = redL[128 + t];
        const float* ar = AHPl + t * 65;
#pragma unroll 8
        for (int m = 0; m < 64; ++m) hz -= ar[m] * ssh[m];
        const float den = pHpdL[t];
        c = hz / ((fabsf(den) > 1e-30f) ? den : 1e-30f);
      }
      cshL[t] = c;
    }
    __syncthreads();
    {
      float accA = 0.f;
#pragma unroll
      for (int kk = 0; kk < 16; ++kk) {
        const int m = wv * 16 + kk;
        accA += Als[m * 65 + lane] * ssh[m];
      }
      partA[t] = accA;
    }
    __syncthreads();
    if (wv == 0) {
      float z = r_ - (partA[lane] + partA[64 + lane] + partA[128 + lane] + partA[192 + lane]);
      if (!valid1) z = 0.f;
      hpL[lane] = z;   // zL
    }
    if (wv == 1 && own2) {
      float acc = 0.f;
      if (valid2) {
#pragma unroll 8
        for (int m = 0; m < 64; ++m) acc += A[(size_t)m * N_ + col2] * ssh[m];
      }
      hpL2[lane] = valid2 ? (r2_ - acc) : 0.f;
    }
    __syncthreads();
    {
      float accP = 0.f;
      if (valid1) {
        for (int j = wv; j <= it; j += 4) accP += cshL[j] * Pb[(size_t)j * N_ + col1];
      }
      partA[t] = accP;
    }
    __syncthreads();
    if (wv == 0) {
      const float z = hpL[lane];
      float pn = z - (partA[lane] + partA[64 + lane] + partA[128 + lane] + partA[192 + lane]);
      if (!valid1) pn = 0.f;
      p_ = pn; pL[lane] = pn;
      const float v0 = wred(d_ * pn * pn);
      const float v1 = wred(pn * pn);
      const float v2 = wred(r_ * pn);
      const float v3 = wred(r_ * z);
      const float v4 = wred(z * z);
      if (lane == 0) {
        atomicAdd(&BBn[(64 + 0) * 32 + bank], v0);
        atomicAdd(&BBn[(64 + 1) * 32 + bank], v1);
        atomicAdd(&BBn[(64 + 2) * 32 + bank], v2);
        atomicAdd(&BBn[(64 + 3) * 32 + bank], v3);
        atomicAdd(&BBn[(64 + 4) * 32 + bank], v4);
      }
    }
    if (wv == 1 && own2) {
      const float z2 = hpL2[lane];
      float accP2 = 0.f;
      if (valid2) {
        for (int j = 0; j <= it; ++j) accP2 += cshL[j] * Pb[(size_t)j * N_ + col2];
      }
      float pn = valid2 ? (z2 - accP2) : 0.f;
      p2_ = pn; pL2[lane] = pn;
      const float v0 = wred(d2_ * pn * pn);
      const float v1 = wred(pn * pn);
      const float v2 = wred(r2_ * pn);
      const float v3 = wred(r2_ * z2);
      const float v4 = wred(z2 * z2);
      if (lane == 0) {
        atomicAdd(&BBn[(64 + 0) * 32 + bank], v0);
        atomicAdd(&BBn[(64 + 1) * 32 + bank], v1);
        atomicAdd(&BBn[(64 + 2) * 32 + bank], v2);
        atomicAdd(&BBn[(64 + 3) * 32 + bank], v3);
        atomicAdd(&BBn[(64 + 4) * 32 + bank], v4);
      }
    }
    __syncthreads();
#pragma unroll
    for (int kk = 0; kk < 16; ++kk) {
      const float s = wred(ur[kk] * pL[lane]);
      if (lane == 0) atomicAdd(&BBn[(wv * 16 + kk) * 32 + bank], s);
    }
    if (wv == 1 && own2) {
      float s = 0.f;
      for (int c = 0; c < nv2; ++c) s += U[(size_t)(base2 + c) * K_ + lane] * pL2[c];
      atomicAdd(&BBn[lane * 32 + bank], s);
    }
    gbar(bar, b, NB, ++ep);
  }

  // ===== epilogue =====
  if (wv == 0 && valid1) out[col1] = t_;
  if (wv == 1 && valid2) out[col2] = t2_;
  if (b == 0 && t == 0) {
    out[N_]     = pgn;
    out[N_ + 1] = convf ? 1.f : 0.f;
  }
}

extern "C" void kernel_launch(void* const* d_in, const int* in_sizes, int n_in,
                              void* d_out, int out_size, void* d_ws, size_t ws_size,
                              hipStream_t stream) {
  (void)in_sizes; (void)n_in; (void)out_size; (void)ws_size;
  const float* g  = (const float*)d_in[0];
  const float* dg = (const float*)d_in[1];
  const float* U  = (const float*)d_in[2];
  const float* A  = (const float*)d_in[3];
  float* out = (float*)d_out;
  float* ws  = (float*)d_ws;

  // Grid strictly from the occupancy API (R2/R5/R7 lesson).
  int dev = 0;
  hipGetDevice(&dev);
  int nCU = 0;
  hipDeviceGetAttribute(&nCU, hipDeviceAttributeMultiprocessorCount, dev);
  if (nCU <= 0) nCU = 256;
  int maxB = 0;
  hipOccupancyMaxActiveBlocksPerMultiprocessor(&maxB, stcg_kernel, BSZ, 0);
  if (maxB <= 0) maxB = 1;
  int nblk = maxB * nCU;
  if (nblk > NC) nblk = NC;
  if (nblk < 391) nblk = 391;  // 2-chunk fallback floor (ceil(782/2))

  void* args[] = {(void*)&g, (void*)&dg, (void*)&U, (void*)&A, (void*)&out, (void*)&ws};
  hipLaunchCooperativeKernel(stcg_kernel, dim3(nblk), dim3(BSZ), args, 0, stream);
}